// Round 1
// baseline (165.021 us; speedup 1.0000x reference)
//
#include <hip/hip_runtime.h>

// All-pole IIR: y[t] = x[t] - sum_{k=1..16} a_k y[t-k], zero initial state.
// Parallelized by chunked warm-up: each thread owns L=128 outputs of one
// channel, warms up from zero state W=320 samples earlier (decay ~rho^320,
// rho <= ~0.9 for a_k = 0.03*N(0,1) => error ~1e-14, exact for t<W chunks).

constexpr int B_ = 32;
constexpr int C_ = 8;
constexpr int T_ = 65536;
constexpr int P_ = 16;
constexpr int BC = B_ * C_;            // 256 channels
constexpr int L_ = 128;                 // outputs per thread
constexpr int W_ = 320;                 // warm-up samples (mult of 16)
constexpr int NCHUNK = T_ / L_;         // 512 chunks per channel
constexpr int WARM_IT = W_ / 16;        // 20
constexpr int OUT_IT = L_ / 16;         // 8
constexpr int NTHREADS = BC * NCHUNK;   // 131072
constexpr int BLOCK = 256;

__global__ __launch_bounds__(BLOCK) void allpole_kernel(
    const float* __restrict__ x, const float* __restrict__ a,
    float* __restrict__ y)
{
    const int gid = blockIdx.x * BLOCK + threadIdx.x;
    const int ch = gid >> 9;              // gid / NCHUNK
    const int ci = gid & (NCHUNK - 1);    // chunk index within channel

    const float* __restrict__ xc = x + (size_t)ch * T_;
    float* __restrict__ yc = y + (size_t)ch * T_;
    const float* __restrict__ ac = a + ch * (P_ + 1);

    const float inv_a0 = 1.0f / ac[0];
    float b[P_ + 1];                      // b[k] = -a_k / a_0
#pragma unroll
    for (int k = 1; k <= P_; ++k) b[k] = -ac[k] * inv_a0;

    // Register ring buffer: h[i] = most recent y at time ≡ i (mod 16).
    float h[16];
#pragma unroll
    for (int i = 0; i < 16; ++i) h[i] = 0.0f;

    const int base = ci * L_ - W_;        // multiple of 16 (may be negative)

    // One macro-step: 16 recurrence steps with compile-time ring indices.
    // Tree the k>=2 terms so the only cross-step dep is the final fmaf(b1,...).
#define STEP16(XS, OS, DO_OUT)                                            \
    _Pragma("unroll")                                                     \
    for (int s = 0; s < 16; ++s) {                                        \
        float c0 = fmaf(b[2],  h[(s - 2)  & 15], (XS)[s]);                \
        c0 = fmaf(b[3],  h[(s - 3)  & 15], c0);                           \
        c0 = fmaf(b[4],  h[(s - 4)  & 15], c0);                           \
        c0 = fmaf(b[5],  h[(s - 5)  & 15], c0);                           \
        float c1 = b[6] * h[(s - 6)  & 15];                               \
        c1 = fmaf(b[7],  h[(s - 7)  & 15], c1);                           \
        c1 = fmaf(b[8],  h[(s - 8)  & 15], c1);                           \
        c1 = fmaf(b[9],  h[(s - 9)  & 15], c1);                           \
        float c2 = b[10] * h[(s - 10) & 15];                              \
        c2 = fmaf(b[11], h[(s - 11) & 15], c2);                           \
        c2 = fmaf(b[12], h[(s - 12) & 15], c2);                           \
        c2 = fmaf(b[13], h[(s - 13) & 15], c2);                           \
        float c3 = b[14] * h[(s - 14) & 15];                              \
        c3 = fmaf(b[15], h[(s - 15) & 15], c3);                           \
        c3 = fmaf(b[16], h[(s - 16) & 15], c3);  /* (s-16)&15 == s: old */ \
        const float pre = (c0 + c1) + (c2 + c3);                          \
        h[s] = fmaf(b[1], h[(s - 1) & 15], pre);                          \
        if (DO_OUT) (OS)[s] = h[s];                                       \
    }

    // ---- Phase A: warm-up (no stores; t<0 reads substituted with 0) ----
    for (int it = 0; it < WARM_IT; ++it) {
        const int t0 = base + it * 16;
        float xs[16];
#pragma unroll
        for (int q = 0; q < 4; ++q) {
            const int tq = t0 + q * 4;             // ≡ 0 mod 4
            const int tsafe = tq >= 0 ? tq : 0;
            float4 v = *reinterpret_cast<const float4*>(xc + tsafe);
            const bool ok = tq >= 0;
            xs[q * 4 + 0] = ok ? v.x : 0.0f;
            xs[q * 4 + 1] = ok ? v.y : 0.0f;
            xs[q * 4 + 2] = ok ? v.z : 0.0f;
            xs[q * 4 + 3] = ok ? v.w : 0.0f;
        }
        float dummy[16];
        STEP16(xs, dummy, false)
    }

    // ---- Phase B: produce and store L=128 outputs ----
    for (int it = 0; it < OUT_IT; ++it) {
        const int t0 = ci * L_ + it * 16;
        float xs[16];
#pragma unroll
        for (int q = 0; q < 4; ++q) {
            float4 v = *reinterpret_cast<const float4*>(xc + t0 + q * 4);
            xs[q * 4 + 0] = v.x; xs[q * 4 + 1] = v.y;
            xs[q * 4 + 2] = v.z; xs[q * 4 + 3] = v.w;
        }
        float os[16];
        STEP16(xs, os, true)
#pragma unroll
        for (int q = 0; q < 4; ++q) {
            float4 v;
            v.x = os[q * 4 + 0]; v.y = os[q * 4 + 1];
            v.z = os[q * 4 + 2]; v.w = os[q * 4 + 3];
            *reinterpret_cast<float4*>(yc + t0 + q * 4) = v;
        }
    }
#undef STEP16
}

extern "C" void kernel_launch(void* const* d_in, const int* in_sizes, int n_in,
                              void* d_out, int out_size, void* d_ws, size_t ws_size,
                              hipStream_t stream) {
    const float* x = (const float*)d_in[0];
    const float* a = (const float*)d_in[1];
    float* y = (float*)d_out;
    const int grid = NTHREADS / BLOCK;  // 512 blocks
    allpole_kernel<<<grid, BLOCK, 0, stream>>>(x, a, y);
}